// Round 7
// baseline (367.447 us; speedup 1.0000x reference)
//
#include <hip/hip_runtime.h>

typedef __attribute__((ext_vector_type(8))) _Float16 f16x8;        // 8 fp16 (4 VGPRs)
typedef __attribute__((ext_vector_type(8))) unsigned short u16x8;  // 16B chunk
typedef __attribute__((ext_vector_type(4))) float f32x4;
typedef unsigned short u16;

#define NDC 1048576UL  // N*D = 2048*512
#define NNC 4194304UL  // N*N

__device__ __forceinline__ u16 f2h(float f) {  // RNE fp16
  _Float16 h = (_Float16)f;
  return __builtin_bit_cast(u16, h);
}

// Async global->LDS DMA, 16B per lane (dest = wave-uniform base + lane*16).
__device__ __forceinline__ void gl_lds16(const u16* g, u16* l) {
  __builtin_amdgcn_global_load_lds(
      (const __attribute__((address_space(1))) void*)g,
      (__attribute__((address_space(3))) void*)l, 16, 0, 0);
}

// ---------------- fp32 -> fp16 convert ----------------
__global__ __launch_bounds__(256) void cvt_h(const float* __restrict__ in,
                                             u16* __restrict__ hi, int n8) {
  int t = blockIdx.x * 256 + threadIdx.x;
  if (t >= n8) return;
  const float4* p = (const float4*)in;
  float4 a = p[2 * t], b = p[2 * t + 1];
  float v[8] = {a.x, a.y, a.z, a.w, b.x, b.y, b.z, b.w};
  u16x8 h;
#pragma unroll
  for (int i = 0; i < 8; ++i) h[i] = f2h(v[i]);
  *(u16x8*)(hi + (size_t)t * 8) = h;
}

// ---------------- MFMA GEMM core (fp16, global_load_lds staging) ----------
// C[m,n] = sum_k A[m,k]*B[n,k], operands row-major [free][k] fp16.
// BM=BN=128, BK=32, 256 threads (4 waves), 64x64/wave via 4x4 mfma 16x16x32.
__device__ __forceinline__ void mfma_core1(u16* s, const u16* __restrict__ A,
                                           const u16* __restrict__ B,
                                           int lda, int ldb, int Kdim,
                                           int m0, int n0, f32x4 acc[4][4]) {
  const int tid = threadIdx.x;
  const int l = tid & 63, w = tid >> 6;
  const int wm = w >> 1, wn = w & 1;
  const int quad = l >> 4, l15 = l & 15;
  const int srow = w * 32 + (l >> 2);  // staging row (and +16)
  const int skc = (l & 3) * 8;         // staging k offset (u16)

  u16* sA = s;
  u16* sB = s + 4096;

  const u16* gA0 = A + (size_t)(m0 + srow) * lda + skc;
  const u16* gB0 = B + (size_t)(n0 + srow) * ldb + skc;
  u16* lA0 = sA + srow * 32 + skc;
  u16* lB0 = sB + srow * 32 + skc;
  const size_t a16 = (size_t)16 * lda, b16 = (size_t)16 * ldb;

  const int afrag = (wm * 64 + l15) * 32 + quad * 8;  // u16 idx; +i*512 rows
  const int bfrag = (wn * 64 + l15) * 32 + quad * 8;

  for (int k0 = 0; k0 < Kdim; k0 += 32) {
    __syncthreads();  // previous tile's ds_reads done before DMA overwrite
    gl_lds16(gA0 + k0, lA0);
    gl_lds16(gA0 + k0 + a16, lA0 + 512);
    gl_lds16(gB0 + k0, lB0);
    gl_lds16(gB0 + k0 + b16, lB0 + 512);
    __syncthreads();  // drains vmcnt (DMA visible)

    f16x8 fa[4], fb[4];
#pragma unroll
    for (int i = 0; i < 4; ++i) fa[i] = *(const f16x8*)(sA + afrag + i * 512);
#pragma unroll
    for (int j = 0; j < 4; ++j) fb[j] = *(const f16x8*)(sB + bfrag + j * 512);
#pragma unroll
    for (int i = 0; i < 4; ++i)
#pragma unroll
      for (int j = 0; j < 4; ++j)
        acc[i][j] = __builtin_amdgcn_mfma_f32_16x16x32_f16(fa[i], fb[j],
                                                           acc[i][j], 0, 0, 0);
  }
}

#define ACC_ZERO()                                   \
  f32x4 acc[4][4];                                   \
  {                                                  \
    const f32x4 zero = {0.0f, 0.0f, 0.0f, 0.0f};     \
    for (int i = 0; i < 4; ++i)                      \
      for (int j = 0; j < 4; ++j) acc[i][j] = zero;  \
  }

#define EPI_COORDS(mbase, nbase)                            \
  const int lane = threadIdx.x & 63;                        \
  const int wave = threadIdx.x >> 6;                        \
  const int quad = lane >> 4, l15 = lane & 15;              \
  const int em = (mbase) + (wave >> 1) * 64 + quad * 4;     \
  const int en = (nbase) + (wave & 1) * 64 + l15;

// QKV (fp16, 1-pass): blockIdx.x = (z<<2)|ntile (12 consecutive blocks share
// the same x rows -> L3 temporal reuse). z=0 Q, z=1 K (row-major fp16 out),
// z=2 V (transposed fp16 out Vt[e][m]).
__global__ __launch_bounds__(256, 2) void gemm_qkv4(
    const u16* __restrict__ xh, const u16* __restrict__ Wq,
    const u16* __restrict__ Wk, const u16* __restrict__ Wv,
    const float* __restrict__ bq, const float* __restrict__ bk,
    const float* __restrict__ bv, u16* __restrict__ Q, u16* __restrict__ K,
    u16* __restrict__ Vt, int ldvt) {
  __shared__ u16 s[8192];
  const int z = blockIdx.x >> 2;
  const int n0 = (blockIdx.x & 3) * 128;
  const int m0 = blockIdx.y * 128;
  const u16* W = (z == 0) ? Wq : (z == 1) ? Wk : Wv;
  const float* bias = (z == 0) ? bq : (z == 1) ? bk : bv;
  ACC_ZERO();
  mfma_core1(s, xh, W, 512, 512, 512, m0, n0, acc);
  EPI_COORDS(m0, n0);
  float bj[4];
#pragma unroll
  for (int j = 0; j < 4; ++j) bj[j] = bias[en + j * 16];
  if (z < 2) {
    u16* O = (z == 0) ? Q : K;
#pragma unroll
    for (int i = 0; i < 4; ++i)
#pragma unroll
      for (int r = 0; r < 4; ++r) {
        size_t row = (size_t)(em + i * 16 + r) * 512;
#pragma unroll
        for (int j = 0; j < 4; ++j)
          O[row + en + j * 16] = f2h(acc[i][j][r] + bj[j]);
      }
  } else {
#pragma unroll
    for (int i = 0; i < 4; ++i)
#pragma unroll
      for (int r = 0; r < 4; ++r) {
        int m = em + i * 16 + r;
#pragma unroll
        for (int j = 0; j < 4; ++j)
          Vt[(size_t)(en + j * 16) * ldvt + m] = f2h(acc[i][j][r] + bj[j]);
      }
  }
}

// Scores S = Q·K^T, fp32 out. 1-D grid 2048: z = wg&7 (XCD batch-pin),
// t = wg>>3, n = t&15 (fastest: 16 consecutive same-XCD blocks share the Q
// m-tile), m = t>>4. Per-XCD working set = one batch's Q+K (4 MB, L2-resident).
__global__ __launch_bounds__(256, 2) void gemm_scores(
    const u16* __restrict__ Q, const u16* __restrict__ K,
    float* __restrict__ S) {
  __shared__ u16 s[8192];
  const int wg = blockIdx.x;
  const int z = wg & 7;
  const int t = wg >> 3;
  const int n0 = (t & 15) * 128;
  const int m0 = (t >> 4) * 128;
  ACC_ZERO();
  mfma_core1(s, Q + z * NDC, K + z * NDC, 512, 512, 512, m0, n0, acc);
  float* Sz = S + z * NNC;
  EPI_COORDS(m0, n0);
#pragma unroll
  for (int i = 0; i < 4; ++i)
#pragma unroll
    for (int r = 0; r < 4; ++r) {
      size_t row = (size_t)(em + i * 16 + r) * 2048;
#pragma unroll
      for (int j = 0; j < 4; ++j) Sz[row + en + j * 16] = acc[i][j][r];
    }
}

// PV with split-K x4 + XCD batch-pin: out[m,e] += sum_k P[m,k] Vt[e][k-col].
// 1-D grid 2048: z = wg&7, t = wg>>3, n = t&3 (fastest: 4 consecutive
// same-XCD blocks share the P (m,kc) block), kc = (t>>2)&3, m = t>>4.
// K-chunk = 512 (16 iters). Partials atomicAdd'ed into zeroed out.
__global__ __launch_bounds__(256, 2) void gemm_pv(
    const u16* __restrict__ P, const u16* __restrict__ Vt,
    float* __restrict__ out) {
  __shared__ u16 s[8192];
  const int wg = blockIdx.x;
  const int z = wg & 7;
  const int t = wg >> 3;
  const int n0 = (t & 3) * 128;
  const int kc = (t >> 2) & 3;
  const int m0 = (t >> 4) * 128;
  const u16* Pz = P + z * 2 * NNC + kc * 512;   // P lda=4096 (in-place over S)
  const u16* Vz = Vt + z * 2048 + kc * 512;     // Vt ldb=16384
  ACC_ZERO();
  mfma_core1(s, Pz, Vz, 4096, 16384, 512, m0, n0, acc);
  float* oz = out + z * NDC;
  EPI_COORDS(m0, n0);
#pragma unroll
  for (int i = 0; i < 4; ++i)
#pragma unroll
    for (int r = 0; r < 4; ++r) {
      size_t row = (size_t)(em + i * 16 + r) * 512;
#pragma unroll
      for (int j = 0; j < 4; ++j)
        atomicAdd(&oz[row + en + j * 16], acc[i][j][r]);
    }
}

// ------- softmax row 2048, IN-PLACE: fp32 row -> fp16 P in row's first half.
__global__ __launch_bounds__(256) void softmax_inplace(float* __restrict__ S) {
  __shared__ float red[8];
  const int tid = threadIdx.x;
  const size_t row = blockIdx.x;
  const float4* src = (const float4*)(S + row * 2048);
  float4 v0 = src[2 * tid], v1 = src[2 * tid + 1];

  float mx = fmaxf(fmaxf(fmaxf(v0.x, v0.y), fmaxf(v0.z, v0.w)),
                   fmaxf(fmaxf(v1.x, v1.y), fmaxf(v1.z, v1.w)));
#pragma unroll
  for (int off = 32; off >= 1; off >>= 1) mx = fmaxf(mx, __shfl_xor(mx, off));
  const int wid = tid >> 6, lane = tid & 63;
  if (lane == 0) red[wid] = mx;
  __syncthreads();
  if (tid == 0) red[4] = fmaxf(fmaxf(red[0], red[1]), fmaxf(red[2], red[3]));
  __syncthreads();
  mx = red[4];

  v0.x = __expf(v0.x - mx); v0.y = __expf(v0.y - mx);
  v0.z = __expf(v0.z - mx); v0.w = __expf(v0.w - mx);
  v1.x = __expf(v1.x - mx); v1.y = __expf(v1.y - mx);
  v1.z = __expf(v1.z - mx); v1.w = __expf(v1.w - mx);

  float sm = v0.x + v0.y + v0.z + v0.w + v1.x + v1.y + v1.z + v1.w;
#pragma unroll
  for (int off = 32; off >= 1; off >>= 1) sm += __shfl_xor(sm, off);
  __syncthreads();
  if (lane == 0) red[wid] = sm;
  __syncthreads();
  if (tid == 0) red[5] = red[0] + red[1] + red[2] + red[3];
  __syncthreads();
  const float inv = 1.0f / red[5];

  u16x8 o;
  o[0] = f2h(v0.x * inv); o[1] = f2h(v0.y * inv);
  o[2] = f2h(v0.z * inv); o[3] = f2h(v0.w * inv);
  o[4] = f2h(v1.x * inv); o[5] = f2h(v1.y * inv);
  o[6] = f2h(v1.z * inv); o[7] = f2h(v1.w * inv);
  *(u16x8*)((u16*)S + row * 4096 + tid * 8) = o;
}

// ================= fp32 fallback (round-0, proven; used only if ws tiny) ====
#define LTILE_M 64
#define LTILE_N 64
#define LTILE_K 32
template <bool B_NT, bool HAS_BIAS>
__device__ __forceinline__ void gemm_body_leg(const float* __restrict__ A,
                                              const float* __restrict__ Bm,
                                              const float* __restrict__ bias,
                                              float* __restrict__ C, int lda,
                                              int ldb, int ldc, int Kdim) {
  __shared__ float As[LTILE_K][LTILE_M + 4];
  __shared__ float Bs[LTILE_K][LTILE_N + 4];
  const int tid = threadIdx.x;
  const int tx = tid & 15, ty = tid >> 4;
  const int m0 = blockIdx.y * LTILE_M, n0 = blockIdx.x * LTILE_N;
  const int am = tid >> 3, ak = (tid & 7) << 2;
  const int bk_ = tid >> 4, bn = (tid & 15) << 2;
  float acc[4][4] = {};
  for (int k0 = 0; k0 < Kdim; k0 += LTILE_K) {
    float4 a0 = *(const float4*)(A + (size_t)(m0 + am) * lda + k0 + ak);
    float4 a1 = *(const float4*)(A + (size_t)(m0 + am + 32) * lda + k0 + ak);
    float4 b0, b1;
    if (B_NT) {
      b0 = *(const float4*)(Bm + (size_t)(n0 + am) * ldb + k0 + ak);
      b1 = *(const float4*)(Bm + (size_t)(n0 + am + 32) * ldb + k0 + ak);
    } else {
      b0 = *(const float4*)(Bm + (size_t)(k0 + bk_) * ldb + n0 + bn);
      b1 = *(const float4*)(Bm + (size_t)(k0 + bk_ + 16) * ldb + n0 + bn);
    }
    __syncthreads();
    As[ak + 0][am] = a0.x; As[ak + 1][am] = a0.y;
    As[ak + 2][am] = a0.z; As[ak + 3][am] = a0.w;
    As[ak + 0][am + 32] = a1.x; As[ak + 1][am + 32] = a1.y;
    As[ak + 2][am + 32] = a1.z; As[ak + 3][am + 32] = a1.w;
    if (B_NT) {
      Bs[ak + 0][am] = b0.x; Bs[ak + 1][am] = b0.y;
      Bs[ak + 2][am] = b0.z; Bs[ak + 3][am] = b0.w;
      Bs[ak + 0][am + 32] = b1.x; Bs[ak + 1][am + 32] = b1.y;
      Bs[ak + 2][am + 32] = b1.z; Bs[ak + 3][am + 32] = b1.w;
    } else {
      *(float4*)&Bs[bk_][bn] = b0;
      *(float4*)&Bs[bk_ + 16][bn] = b1;
    }
    __syncthreads();
#pragma unroll
    for (int kk = 0; kk < LTILE_K; ++kk) {
      float4 av = *(const float4*)&As[kk][ty << 2];
      float4 bv4 = *(const float4*)&Bs[kk][tx << 2];
      acc[0][0] += av.x * bv4.x; acc[0][1] += av.x * bv4.y;
      acc[0][2] += av.x * bv4.z; acc[0][3] += av.x * bv4.w;
      acc[1][0] += av.y * bv4.x; acc[1][1] += av.y * bv4.y;
      acc[1][2] += av.y * bv4.z; acc[1][3] += av.y * bv4.w;
      acc[2][0] += av.z * bv4.x; acc[2][1] += av.z * bv4.y;
      acc[2][2] += av.z * bv4.z; acc[2][3] += av.z * bv4.w;
      acc[3][0] += av.w * bv4.x; acc[3][1] += av.w * bv4.y;
      acc[3][2] += av.w * bv4.z; acc[3][3] += av.w * bv4.w;
    }
  }
  float4 badd = {0.0f, 0.0f, 0.0f, 0.0f};
  if (HAS_BIAS) badd = *(const float4*)(bias + n0 + (tx << 2));
#pragma unroll
  for (int r = 0; r < 4; ++r) {
    float4 o;
    o.x = acc[r][0] + badd.x; o.y = acc[r][1] + badd.y;
    o.z = acc[r][2] + badd.z; o.w = acc[r][3] + badd.w;
    *(float4*)(C + (size_t)(m0 + (ty << 2) + r) * ldc + n0 + (tx << 2)) = o;
  }
}
template <bool B_NT, bool HAS_BIAS>
__global__ __launch_bounds__(256, 4) void gemm_leg(const float* A, const float* Bm,
                                                   const float* bias, float* C,
                                                   int lda, int ldb, int ldc,
                                                   int Kdim) {
  gemm_body_leg<B_NT, HAS_BIAS>(A, Bm, bias, C, lda, ldb, ldc, Kdim);
}
__global__ __launch_bounds__(256, 4) void qkv_leg(
    const float* x, const float* Wq, const float* bq, const float* Wk,
    const float* bk, const float* Wv, const float* bv, float* Q, float* K,
    float* V) {
  const float *W, *bias;
  float* C;
  if (blockIdx.z == 0) { W = Wq; bias = bq; C = Q; }
  else if (blockIdx.z == 1) { W = Wk; bias = bk; C = K; }
  else { W = Wv; bias = bv; C = V; }
  gemm_body_leg<true, true>(x, W, bias, C, 512, 512, 512, 512);
}
__global__ __launch_bounds__(256) void softmax_leg(float* S, int ncols) {
  __shared__ float red[8];
  float4* rowp = (float4*)(S + (size_t)blockIdx.x * ncols);
  const int tid = threadIdx.x;
  float4 v0 = rowp[tid], v1 = rowp[tid + 256];
  float mx = fmaxf(fmaxf(fmaxf(v0.x, v0.y), fmaxf(v0.z, v0.w)),
                   fmaxf(fmaxf(v1.x, v1.y), fmaxf(v1.z, v1.w)));
#pragma unroll
  for (int off = 32; off >= 1; off >>= 1) mx = fmaxf(mx, __shfl_xor(mx, off));
  const int wid = tid >> 6, lane = tid & 63;
  if (lane == 0) red[wid] = mx;
  __syncthreads();
  if (tid == 0) red[4] = fmaxf(fmaxf(red[0], red[1]), fmaxf(red[2], red[3]));
  __syncthreads();
  mx = red[4];
  v0.x = __expf(v0.x - mx); v0.y = __expf(v0.y - mx);
  v0.z = __expf(v0.z - mx); v0.w = __expf(v0.w - mx);
  v1.x = __expf(v1.x - mx); v1.y = __expf(v1.y - mx);
  v1.w = __expf(v1.w - mx); v1.z = __expf(v1.z - mx);
  float sm = v0.x + v0.y + v0.z + v0.w + v1.x + v1.y + v1.z + v1.w;
#pragma unroll
  for (int off = 32; off >= 1; off >>= 1) sm += __shfl_xor(sm, off);
  __syncthreads();
  if (lane == 0) red[wid] = sm;
  __syncthreads();
  if (tid == 0) red[5] = red[0] + red[1] + red[2] + red[3];
  __syncthreads();
  const float inv = 1.0f / red[5];
  v0.x *= inv; v0.y *= inv; v0.z *= inv; v0.w *= inv;
  v1.x *= inv; v1.y *= inv; v1.z *= inv; v1.w *= inv;
  rowp[tid] = v0;
  rowp[tid + 256] = v1;
}

// ================================ host ================================
extern "C" void kernel_launch(void* const* d_in, const int* in_sizes, int n_in,
                              void* d_out, int out_size, void* d_ws,
                              size_t ws_size, hipStream_t stream) {
  (void)in_sizes; (void)n_in;
  const int B = 8, N = 2048, D = 512;
  const size_t ND = (size_t)N * D;
  const size_t NN = (size_t)N * N;
  const float* x = (const float*)d_in[0];
  const float* Wf[3] = {(const float*)d_in[1], (const float*)d_in[3],
                        (const float*)d_in[5]};
  const float* bq = (const float*)d_in[2];
  const float* bk = (const float*)d_in[4];
  const float* bv = (const float*)d_in[6];
  float* out = (float*)d_out;

  char* w = (char*)d_ws;
  auto take = [&](size_t bytes) {
    char* p = w;
    w += (bytes + 255) & ~(size_t)255;
    return p;
  };

  if (ws_size >= 190000000ULL) {
    // ---- fp16 pipeline, fully batched (~186 MB), all GEMMs 1-pass.
    // P written in place over S; x fp16 overlapped into S (dead after QKV).
    u16* Wh[3];
    for (int i = 0; i < 3; ++i) Wh[i] = (u16*)take(524288);
    u16* Q  = (u16*)take(2 * B * ND);  // 16.78 MB each
    u16* K  = (u16*)take(2 * B * ND);
    u16* Vt = (u16*)take(2 * B * ND);
    float* S = (float*)w;              // 134.2 MB region
    u16* xh = (u16*)take(2 * B * ND);  // inside S, dead after QKV

    cvt_h<<<8192, 256, 0, stream>>>(x, xh, (int)(B * ND / 8));
    for (int i = 0; i < 3; ++i)
      cvt_h<<<128, 256, 0, stream>>>(Wf[i], Wh[i], 32768);
    gemm_qkv4<<<dim3(12, 128), 256, 0, stream>>>(
        xh, Wh[0], Wh[1], Wh[2], bq, bk, bv, Q, K, Vt, B * N);
    // scores: XCD batch-pinned 1-D grid
    gemm_scores<<<2048, 256, 0, stream>>>(Q, K, S);
    // softmax: in-place fp16 P (row stride 4096 u16)
    softmax_inplace<<<B * N, 256, 0, stream>>>(S);
    // PV: split-K x4 + batch pin; out zero-init then atomicAdd partials
    hipMemsetAsync(out, 0, (size_t)out_size * sizeof(float), stream);
    gemm_pv<<<2048, 256, 0, stream>>>((const u16*)S, Vt, out);
  } else {
    // ---- fp32 fallback (round-0 path, 29.4 MB) ----
    float* ws = (float*)d_ws;
    float* Q = ws;
    float* Kp = ws + ND;
    float* V = ws + 2 * ND;
    float* S = ws + 3 * ND;
    for (int b = 0; b < B; ++b) {
      const float* xb = x + b * ND;
      float* outb = out + b * ND;
      qkv_leg<<<dim3(8, 32, 3), 256, 0, stream>>>(xb, Wf[0], bq, Wf[1], bk,
                                                  Wf[2], bv, Q, Kp, V);
      gemm_leg<true, false><<<dim3(32, 32), 256, 0, stream>>>(Q, Kp, nullptr, S,
                                                              512, 512, 2048, 512);
      softmax_leg<<<N, 256, 0, stream>>>(S, N);
      gemm_leg<false, false><<<dim3(8, 32), 256, 0, stream>>>(S, V, nullptr,
                                                              outb, 2048, 512,
                                                              512, 2048);
    }
  }
}

// Round 8
// 286.898 us; speedup vs baseline: 1.2808x; 1.2808x over previous
//
#include <hip/hip_runtime.h>

typedef __attribute__((ext_vector_type(8))) _Float16 f16x8;        // 8 fp16 (4 VGPRs)
typedef __attribute__((ext_vector_type(8))) unsigned short u16x8;  // 16B chunk
typedef __attribute__((ext_vector_type(4))) float f32x4;
typedef unsigned short u16;

#define NDC 1048576UL  // N*D = 2048*512
#define NNC 4194304UL  // N*N

__device__ __forceinline__ u16 f2h(float f) {  // RNE fp16
  _Float16 h = (_Float16)f;
  return __builtin_bit_cast(u16, h);
}

// Async global->LDS DMA, 16B per lane (dest = wave-uniform base + lane*16).
__device__ __forceinline__ void gl_lds16(const u16* g, u16* l) {
  __builtin_amdgcn_global_load_lds(
      (const __attribute__((address_space(1))) void*)g,
      (__attribute__((address_space(3))) void*)l, 16, 0, 0);
}

// ---------------- fp32 -> fp16 convert ----------------
__global__ __launch_bounds__(256) void cvt_h(const float* __restrict__ in,
                                             u16* __restrict__ hi, int n8) {
  int t = blockIdx.x * 256 + threadIdx.x;
  if (t >= n8) return;
  const float4* p = (const float4*)in;
  float4 a = p[2 * t], b = p[2 * t + 1];
  float v[8] = {a.x, a.y, a.z, a.w, b.x, b.y, b.z, b.w};
  u16x8 h;
#pragma unroll
  for (int i = 0; i < 8; ++i) h[i] = f2h(v[i]);
  *(u16x8*)(hi + (size_t)t * 8) = h;
}

// ---------------- MFMA GEMM core 128x128 (fp16, DMA staging) ----------
// C[m,n] = sum_k A[m,k]*B[n,k], operands row-major [free][k] fp16.
// BM=BN=128, BK=32, 256 threads (4 waves 2x2), 64x64/wave via 4x4 mfma.
__device__ __forceinline__ void mfma_core1(u16* s, const u16* __restrict__ A,
                                           const u16* __restrict__ B,
                                           int lda, int ldb, int Kdim,
                                           int m0, int n0, f32x4 acc[4][4]) {
  const int tid = threadIdx.x;
  const int l = tid & 63, w = tid >> 6;
  const int wm = w >> 1, wn = w & 1;
  const int quad = l >> 4, l15 = l & 15;
  const int srow = w * 32 + (l >> 2);  // staging row (and +16)
  const int skc = (l & 3) * 8;         // staging k offset (u16)

  u16* sA = s;
  u16* sB = s + 4096;

  const u16* gA0 = A + (size_t)(m0 + srow) * lda + skc;
  const u16* gB0 = B + (size_t)(n0 + srow) * ldb + skc;
  u16* lA0 = sA + srow * 32 + skc;
  u16* lB0 = sB + srow * 32 + skc;
  const size_t a16 = (size_t)16 * lda, b16 = (size_t)16 * ldb;

  const int afrag = (wm * 64 + l15) * 32 + quad * 8;  // u16 idx; +i*512 rows
  const int bfrag = (wn * 64 + l15) * 32 + quad * 8;

  for (int k0 = 0; k0 < Kdim; k0 += 32) {
    __syncthreads();  // previous tile's ds_reads done before DMA overwrite
    gl_lds16(gA0 + k0, lA0);
    gl_lds16(gA0 + k0 + a16, lA0 + 512);
    gl_lds16(gB0 + k0, lB0);
    gl_lds16(gB0 + k0 + b16, lB0 + 512);
    __syncthreads();  // drains vmcnt (DMA visible)

    f16x8 fa[4], fb[4];
#pragma unroll
    for (int i = 0; i < 4; ++i) fa[i] = *(const f16x8*)(sA + afrag + i * 512);
#pragma unroll
    for (int j = 0; j < 4; ++j) fb[j] = *(const f16x8*)(sB + bfrag + j * 512);
#pragma unroll
    for (int i = 0; i < 4; ++i)
#pragma unroll
      for (int j = 0; j < 4; ++j)
        acc[i][j] = __builtin_amdgcn_mfma_f32_16x16x32_f16(fa[i], fb[j],
                                                           acc[i][j], 0, 0, 0);
  }
}

// ---------------- MFMA GEMM core 128x64 (fp16, DMA staging) -----------
// BM=128, BN=64, BK=32; 4 waves 2(m)x2(n), 64x32/wave via 4x2 mfma tiles.
// sA 8 KB (2 DMA), sB 4 KB (1 DMA: wave w stages B rows w*16..w*16+15).
__device__ __forceinline__ void mfma_core64(u16* s, const u16* __restrict__ A,
                                            const u16* __restrict__ B,
                                            int lda, int ldb, int Kdim,
                                            int m0, int n0, f32x4 acc[4][2]) {
  const int tid = threadIdx.x;
  const int l = tid & 63, w = tid >> 6;
  const int wm = w >> 1, wn = w & 1;
  const int quad = l >> 4, l15 = l & 15;
  const int srow = w * 32 + (l >> 2);   // A staging row (and +16)
  const int brow = w * 16 + (l >> 2);   // B staging row (64 total)
  const int skc = (l & 3) * 8;          // staging k offset (u16)

  u16* sA = s;
  u16* sB = s + 4096;

  const u16* gA0 = A + (size_t)(m0 + srow) * lda + skc;
  const u16* gB0 = B + (size_t)(n0 + brow) * ldb + skc;
  u16* lA0 = sA + srow * 32 + skc;
  u16* lB0 = sB + brow * 32 + skc;
  const size_t a16 = (size_t)16 * lda;

  const int afrag = (wm * 64 + l15) * 32 + quad * 8;  // +i*512
  const int bfrag = (wn * 32 + l15) * 32 + quad * 8;  // +j*512

  for (int k0 = 0; k0 < Kdim; k0 += 32) {
    __syncthreads();
    gl_lds16(gA0 + k0, lA0);
    gl_lds16(gA0 + k0 + a16, lA0 + 512);
    gl_lds16(gB0 + k0, lB0);
    __syncthreads();

    f16x8 fa[4], fb[2];
#pragma unroll
    for (int i = 0; i < 4; ++i) fa[i] = *(const f16x8*)(sA + afrag + i * 512);
#pragma unroll
    for (int j = 0; j < 2; ++j) fb[j] = *(const f16x8*)(sB + bfrag + j * 512);
#pragma unroll
    for (int i = 0; i < 4; ++i)
#pragma unroll
      for (int j = 0; j < 2; ++j)
        acc[i][j] = __builtin_amdgcn_mfma_f32_16x16x32_f16(fa[i], fb[j],
                                                           acc[i][j], 0, 0, 0);
  }
}

#define ACC_ZERO()                                   \
  f32x4 acc[4][4];                                   \
  {                                                  \
    const f32x4 zero = {0.0f, 0.0f, 0.0f, 0.0f};     \
    for (int i = 0; i < 4; ++i)                      \
      for (int j = 0; j < 4; ++j) acc[i][j] = zero;  \
  }

#define EPI_COORDS(mbase, nbase)                            \
  const int lane = threadIdx.x & 63;                        \
  const int wave = threadIdx.x >> 6;                        \
  const int quad = lane >> 4, l15 = lane & 15;              \
  const int em = (mbase) + (wave >> 1) * 64 + quad * 4;     \
  const int en = (nbase) + (wave & 1) * 64 + l15;

// QKV (fp16, 1-pass): blockIdx.x = (z<<2)|ntile. z=0 Q, z=1 K (row-major),
// z=2 V (transposed fp16 out Vt[e][m]).
__global__ __launch_bounds__(256, 2) void gemm_qkv4(
    const u16* __restrict__ xh, const u16* __restrict__ Wq,
    const u16* __restrict__ Wk, const u16* __restrict__ Wv,
    const float* __restrict__ bq, const float* __restrict__ bk,
    const float* __restrict__ bv, u16* __restrict__ Q, u16* __restrict__ K,
    u16* __restrict__ Vt, int ldvt) {
  __shared__ u16 s[8192];
  const int z = blockIdx.x >> 2;
  const int n0 = (blockIdx.x & 3) * 128;
  const int m0 = blockIdx.y * 128;
  const u16* W = (z == 0) ? Wq : (z == 1) ? Wk : Wv;
  const float* bias = (z == 0) ? bq : (z == 1) ? bk : bv;
  ACC_ZERO();
  mfma_core1(s, xh, W, 512, 512, 512, m0, n0, acc);
  EPI_COORDS(m0, n0);
  float bj[4];
#pragma unroll
  for (int j = 0; j < 4; ++j) bj[j] = bias[en + j * 16];
  if (z < 2) {
    u16* O = (z == 0) ? Q : K;
#pragma unroll
    for (int i = 0; i < 4; ++i)
#pragma unroll
      for (int r = 0; r < 4; ++r) {
        size_t row = (size_t)(em + i * 16 + r) * 512;
#pragma unroll
        for (int j = 0; j < 4; ++j)
          O[row + en + j * 16] = f2h(acc[i][j][r] + bj[j]);
      }
  } else {
#pragma unroll
    for (int i = 0; i < 4; ++i)
#pragma unroll
      for (int r = 0; r < 4; ++r) {
        int m = em + i * 16 + r;
#pragma unroll
        for (int j = 0; j < 4; ++j)
          Vt[(size_t)(en + j * 16) * ldvt + m] = f2h(acc[i][j][r] + bj[j]);
      }
  }
}

// Scores S = Q·K^T, fp32 out. 1-D grid 2048: z = wg&7 (XCD batch-pin),
// t = wg>>3, n = t&15 (16 consecutive same-XCD blocks share the Q m-tile),
// m = t>>4. Per-XCD working set = one batch's Q+K (4 MB, L2-resident).
__global__ __launch_bounds__(256, 2) void gemm_scores(
    const u16* __restrict__ Q, const u16* __restrict__ K,
    float* __restrict__ S) {
  __shared__ u16 s[8192];
  const int wg = blockIdx.x;
  const int z = wg & 7;
  const int t = wg >> 3;
  const int n0 = (t & 15) * 128;
  const int m0 = (t >> 4) * 128;
  ACC_ZERO();
  mfma_core1(s, Q + z * NDC, K + z * NDC, 512, 512, 512, m0, n0, acc);
  float* Sz = S + z * NNC;
  EPI_COORDS(m0, n0);
#pragma unroll
  for (int i = 0; i < 4; ++i)
#pragma unroll
    for (int r = 0; r < 4; ++r) {
      size_t row = (size_t)(em + i * 16 + r) * 2048;
#pragma unroll
      for (int j = 0; j < 4; ++j) Sz[row + en + j * 16] = acc[i][j][r];
    }
}

// PV: out[m,e] = sum_k P[m,k] Vt[e][k]. 128x64 tiles -> 1024 blocks (4/CU).
// 1-D grid: z = wg&7 (XCD pin), t = wg>>3, n = t&7 (8 consecutive same-XCD
// blocks share the P m-block), m = t>>3. Direct stores, deterministic.
__global__ __launch_bounds__(256, 4) void gemm_pv64(
    const u16* __restrict__ P, const u16* __restrict__ Vt,
    float* __restrict__ out) {
  __shared__ u16 s[6144];
  const int wg = blockIdx.x;
  const int z = wg & 7;
  const int t = wg >> 3;
  const int n0 = (t & 7) * 64;
  const int m0 = (t >> 3) * 128;
  const u16* Pz = P + z * 2 * NNC;   // P lda=4096 (in-place over S)
  const u16* Vz = Vt + z * 2048;     // Vt ldb=16384
  f32x4 acc[4][2];
  {
    const f32x4 zero = {0.0f, 0.0f, 0.0f, 0.0f};
    for (int i = 0; i < 4; ++i)
      for (int j = 0; j < 2; ++j) acc[i][j] = zero;
  }
  mfma_core64(s, Pz, Vz, 4096, 16384, 2048, m0, n0, acc);
  float* oz = out + z * NDC;
  const int lane = threadIdx.x & 63;
  const int wave = threadIdx.x >> 6;
  const int quad = lane >> 4, l15 = lane & 15;
  const int em = m0 + (wave >> 1) * 64 + quad * 4;
  const int en = n0 + (wave & 1) * 32 + l15;
#pragma unroll
  for (int i = 0; i < 4; ++i)
#pragma unroll
    for (int r = 0; r < 4; ++r) {
      size_t row = (size_t)(em + i * 16 + r) * 512;
#pragma unroll
      for (int j = 0; j < 2; ++j) oz[row + en + j * 16] = acc[i][j][r];
    }
}

// ------- softmax row 2048, IN-PLACE: fp32 row -> fp16 P in row's first half.
__global__ __launch_bounds__(256) void softmax_inplace(float* __restrict__ S) {
  __shared__ float red[8];
  const int tid = threadIdx.x;
  const size_t row = blockIdx.x;
  const float4* src = (const float4*)(S + row * 2048);
  float4 v0 = src[2 * tid], v1 = src[2 * tid + 1];

  float mx = fmaxf(fmaxf(fmaxf(v0.x, v0.y), fmaxf(v0.z, v0.w)),
                   fmaxf(fmaxf(v1.x, v1.y), fmaxf(v1.z, v1.w)));
#pragma unroll
  for (int off = 32; off >= 1; off >>= 1) mx = fmaxf(mx, __shfl_xor(mx, off));
  const int wid = tid >> 6, lane = tid & 63;
  if (lane == 0) red[wid] = mx;
  __syncthreads();
  if (tid == 0) red[4] = fmaxf(fmaxf(red[0], red[1]), fmaxf(red[2], red[3]));
  __syncthreads();
  mx = red[4];

  v0.x = __expf(v0.x - mx); v0.y = __expf(v0.y - mx);
  v0.z = __expf(v0.z - mx); v0.w = __expf(v0.w - mx);
  v1.x = __expf(v1.x - mx); v1.y = __expf(v1.y - mx);
  v1.z = __expf(v1.z - mx); v1.w = __expf(v1.w - mx);

  float sm = v0.x + v0.y + v0.z + v0.w + v1.x + v1.y + v1.z + v1.w;
#pragma unroll
  for (int off = 32; off >= 1; off >>= 1) sm += __shfl_xor(sm, off);
  __syncthreads();
  if (lane == 0) red[wid] = sm;
  __syncthreads();
  if (tid == 0) red[5] = red[0] + red[1] + red[2] + red[3];
  __syncthreads();
  const float inv = 1.0f / red[5];

  u16x8 o;
  o[0] = f2h(v0.x * inv); o[1] = f2h(v0.y * inv);
  o[2] = f2h(v0.z * inv); o[3] = f2h(v0.w * inv);
  o[4] = f2h(v1.x * inv); o[5] = f2h(v1.y * inv);
  o[6] = f2h(v1.z * inv); o[7] = f2h(v1.w * inv);
  *(u16x8*)((u16*)S + row * 4096 + tid * 8) = o;
}

// ================= fp32 fallback (round-0, proven; used only if ws tiny) ====
#define LTILE_M 64
#define LTILE_N 64
#define LTILE_K 32
template <bool B_NT, bool HAS_BIAS>
__device__ __forceinline__ void gemm_body_leg(const float* __restrict__ A,
                                              const float* __restrict__ Bm,
                                              const float* __restrict__ bias,
                                              float* __restrict__ C, int lda,
                                              int ldb, int ldc, int Kdim) {
  __shared__ float As[LTILE_K][LTILE_M + 4];
  __shared__ float Bs[LTILE_K][LTILE_N + 4];
  const int tid = threadIdx.x;
  const int tx = tid & 15, ty = tid >> 4;
  const int m0 = blockIdx.y * LTILE_M, n0 = blockIdx.x * LTILE_N;
  const int am = tid >> 3, ak = (tid & 7) << 2;
  const int bk_ = tid >> 4, bn = (tid & 15) << 2;
  float acc[4][4] = {};
  for (int k0 = 0; k0 < Kdim; k0 += LTILE_K) {
    float4 a0 = *(const float4*)(A + (size_t)(m0 + am) * lda + k0 + ak);
    float4 a1 = *(const float4*)(A + (size_t)(m0 + am + 32) * lda + k0 + ak);
    float4 b0, b1;
    if (B_NT) {
      b0 = *(const float4*)(Bm + (size_t)(n0 + am) * ldb + k0 + ak);
      b1 = *(const float4*)(Bm + (size_t)(n0 + am + 32) * ldb + k0 + ak);
    } else {
      b0 = *(const float4*)(Bm + (size_t)(k0 + bk_) * ldb + n0 + bn);
      b1 = *(const float4*)(Bm + (size_t)(k0 + bk_ + 16) * ldb + n0 + bn);
    }
    __syncthreads();
    As[ak + 0][am] = a0.x; As[ak + 1][am] = a0.y;
    As[ak + 2][am] = a0.z; As[ak + 3][am] = a0.w;
    As[ak + 0][am + 32] = a1.x; As[ak + 1][am + 32] = a1.y;
    As[ak + 2][am + 32] = a1.z; As[ak + 3][am + 32] = a1.w;
    if (B_NT) {
      Bs[ak + 0][am] = b0.x; Bs[ak + 1][am] = b0.y;
      Bs[ak + 2][am] = b0.z; Bs[ak + 3][am] = b0.w;
      Bs[ak + 0][am + 32] = b1.x; Bs[ak + 1][am + 32] = b1.y;
      Bs[ak + 2][am + 32] = b1.z; Bs[ak + 3][am + 32] = b1.w;
    } else {
      *(float4*)&Bs[bk_][bn] = b0;
      *(float4*)&Bs[bk_ + 16][bn] = b1;
    }
    __syncthreads();
#pragma unroll
    for (int kk = 0; kk < LTILE_K; ++kk) {
      float4 av = *(const float4*)&As[kk][ty << 2];
      float4 bv4 = *(const float4*)&Bs[kk][tx << 2];
      acc[0][0] += av.x * bv4.x; acc[0][1] += av.x * bv4.y;
      acc[0][2] += av.x * bv4.z; acc[0][3] += av.x * bv4.w;
      acc[1][0] += av.y * bv4.x; acc[1][1] += av.y * bv4.y;
      acc[1][2] += av.y * bv4.z; acc[1][3] += av.y * bv4.w;
      acc[2][0] += av.z * bv4.x; acc[2][1] += av.z * bv4.y;
      acc[2][2] += av.z * bv4.z; acc[2][3] += av.z * bv4.w;
      acc[3][0] += av.w * bv4.x; acc[3][1] += av.w * bv4.y;
      acc[3][2] += av.w * bv4.z; acc[3][3] += av.w * bv4.w;
    }
  }
  float4 badd = {0.0f, 0.0f, 0.0f, 0.0f};
  if (HAS_BIAS) badd = *(const float4*)(bias + n0 + (tx << 2));
#pragma unroll
  for (int r = 0; r < 4; ++r) {
    float4 o;
    o.x = acc[r][0] + badd.x; o.y = acc[r][1] + badd.y;
    o.z = acc[r][2] + badd.z; o.w = acc[r][3] + badd.w;
    *(float4*)(C + (size_t)(m0 + (ty << 2) + r) * ldc + n0 + (tx << 2)) = o;
  }
}
template <bool B_NT, bool HAS_BIAS>
__global__ __launch_bounds__(256, 4) void gemm_leg(const float* A, const float* Bm,
                                                   const float* bias, float* C,
                                                   int lda, int ldb, int ldc,
                                                   int Kdim) {
  gemm_body_leg<B_NT, HAS_BIAS>(A, Bm, bias, C, lda, ldb, ldc, Kdim);
}
__global__ __launch_bounds__(256, 4) void qkv_leg(
    const float* x, const float* Wq, const float* bq, const float* Wk,
    const float* bk, const float* Wv, const float* bv, float* Q, float* K,
    float* V) {
  const float *W, *bias;
  float* C;
  if (blockIdx.z == 0) { W = Wq; bias = bq; C = Q; }
  else if (blockIdx.z == 1) { W = Wk; bias = bk; C = K; }
  else { W = Wv; bias = bv; C = V; }
  gemm_body_leg<true, true>(x, W, bias, C, 512, 512, 512, 512);
}
__global__ __launch_bounds__(256) void softmax_leg(float* S, int ncols) {
  __shared__ float red[8];
  float4* rowp = (float4*)(S + (size_t)blockIdx.x * ncols);
  const int tid = threadIdx.x;
  float4 v0 = rowp[tid], v1 = rowp[tid + 256];
  float mx = fmaxf(fmaxf(fmaxf(v0.x, v0.y), fmaxf(v0.z, v0.w)),
                   fmaxf(fmaxf(v1.x, v1.y), fmaxf(v1.z, v1.w)));
#pragma unroll
  for (int off = 32; off >= 1; off >>= 1) mx = fmaxf(mx, __shfl_xor(mx, off));
  const int wid = tid >> 6, lane = tid & 63;
  if (lane == 0) red[wid] = mx;
  __syncthreads();
  if (tid == 0) red[4] = fmaxf(fmaxf(red[0], red[1]), fmaxf(red[2], red[3]));
  __syncthreads();
  mx = red[4];
  v0.x = __expf(v0.x - mx); v0.y = __expf(v0.y - mx);
  v0.z = __expf(v0.z - mx); v0.w = __expf(v0.w - mx);
  v1.x = __expf(v1.x - mx); v1.y = __expf(v1.y - mx);
  v1.w = __expf(v1.w - mx); v1.z = __expf(v1.z - mx);
  float sm = v0.x + v0.y + v0.z + v0.w + v1.x + v1.y + v1.z + v1.w;
#pragma unroll
  for (int off = 32; off >= 1; off >>= 1) sm += __shfl_xor(sm, off);
  __syncthreads();
  if (lane == 0) red[wid] = sm;
  __syncthreads();
  if (tid == 0) red[5] = red[0] + red[1] + red[2] + red[3];
  __syncthreads();
  const float inv = 1.0f / red[5];
  v0.x *= inv; v0.y *= inv; v0.z *= inv; v0.w *= inv;
  v1.x *= inv; v1.y *= inv; v1.z *= inv; v1.w *= inv;
  rowp[tid] = v0;
  rowp[tid + 256] = v1;
}

// ================================ host ================================
extern "C" void kernel_launch(void* const* d_in, const int* in_sizes, int n_in,
                              void* d_out, int out_size, void* d_ws,
                              size_t ws_size, hipStream_t stream) {
  (void)in_sizes; (void)n_in; (void)out_size;
  const int B = 8, N = 2048, D = 512;
  const size_t ND = (size_t)N * D;
  const size_t NN = (size_t)N * N;
  const float* x = (const float*)d_in[0];
  const float* Wf[3] = {(const float*)d_in[1], (const float*)d_in[3],
                        (const float*)d_in[5]};
  const float* bq = (const float*)d_in[2];
  const float* bk = (const float*)d_in[4];
  const float* bv = (const float*)d_in[6];
  float* out = (float*)d_out;

  char* w = (char*)d_ws;
  auto take = [&](size_t bytes) {
    char* p = w;
    w += (bytes + 255) & ~(size_t)255;
    return p;
  };

  if (ws_size >= 190000000ULL) {
    // ---- fp16 pipeline, fully batched (~186 MB), all GEMMs 1-pass.
    // P written in place over S; x fp16 overlapped into S (dead after QKV).
    u16* Wh[3];
    for (int i = 0; i < 3; ++i) Wh[i] = (u16*)take(524288);
    u16* Q  = (u16*)take(2 * B * ND);  // 16.78 MB each
    u16* K  = (u16*)take(2 * B * ND);
    u16* Vt = (u16*)take(2 * B * ND);
    float* S = (float*)w;              // 134.2 MB region
    u16* xh = (u16*)take(2 * B * ND);  // inside S, dead after QKV

    cvt_h<<<8192, 256, 0, stream>>>(x, xh, (int)(B * ND / 8));
    for (int i = 0; i < 3; ++i)
      cvt_h<<<128, 256, 0, stream>>>(Wf[i], Wh[i], 32768);
    gemm_qkv4<<<dim3(12, 128), 256, 0, stream>>>(
        xh, Wh[0], Wh[1], Wh[2], bq, bk, bv, Q, K, Vt, B * N);
    // scores: XCD batch-pinned 1-D grid (8 blocks/CU)
    gemm_scores<<<2048, 256, 0, stream>>>(Q, K, S);
    // softmax: in-place fp16 P (row stride 4096 u16)
    softmax_inplace<<<B * N, 256, 0, stream>>>(S);
    // PV: 128x64 tiles, XCD batch-pinned, 1024 blocks (4/CU), direct stores
    gemm_pv64<<<1024, 256, 0, stream>>>((const u16*)S, Vt, out);
  } else {
    // ---- fp32 fallback (round-0 path, 29.4 MB) ----
    float* ws = (float*)d_ws;
    float* Q = ws;
    float* Kp = ws + ND;
    float* V = ws + 2 * ND;
    float* S = ws + 3 * ND;
    for (int b = 0; b < B; ++b) {
      const float* xb = x + b * ND;
      float* outb = out + b * ND;
      qkv_leg<<<dim3(8, 32, 3), 256, 0, stream>>>(xb, Wf[0], bq, Wf[1], bk,
                                                  Wf[2], bv, Q, Kp, V);
      gemm_leg<true, false><<<dim3(32, 32), 256, 0, stream>>>(Q, Kp, nullptr, S,
                                                              512, 512, 2048, 512);
      softmax_leg<<<N, 256, 0, stream>>>(S, N);
      gemm_leg<false, false><<<dim3(8, 32), 256, 0, stream>>>(S, V, nullptr,
                                                              outb, 2048, 512,
                                                              512, 2048);
    }
  }
}